// Round 3
// baseline (1134.865 us; speedup 1.0000x reference)
//
#include <hip/hip_runtime.h>
#include <math.h>

#define N 8192
#define IN_DIM 128
#define HID 32

#define WIN 512           // k-window per stage
#define NWIN (N / WIN)    // 16
#define RSTRIDE 65        // reduction scratch stride (odd: conflict-free)

typedef _Float16 h2 __attribute__((ext_vector_type(2)));
typedef _Float16 h4 __attribute__((ext_vector_type(4)));

__device__ __forceinline__ h2 bch2(unsigned u) {
    union { unsigned u; h2 h; } x; x.u = u; return x.h;
}

#if defined(__has_builtin)
#if __has_builtin(__builtin_amdgcn_fdot2)
#define HAVE_FDOT2 1
#endif
#endif

__device__ __forceinline__ float dot2acc(h2 a, h2 b, float c) {
#ifdef HAVE_FDOT2
    return __builtin_amdgcn_fdot2(a, b, c, false);
#else
    return fmaf((float)a.x, (float)b.x, fmaf((float)a.y, (float)b.y, c));
#endif
}

// dinv[i] = 1/sqrt(1 + sum_j adj[i][j]); also write fp16 copy of adj.
__global__ __launch_bounds__(256) void k_prep(const float* __restrict__ adj,
                                              _Float16* __restrict__ adjh,
                                              float* __restrict__ dinv) {
    int row = blockIdx.x;
    int t = threadIdx.x;
    const float4* rp = (const float4*)(adj + (size_t)row * N);
    h4* hp = (h4*)(adjh + (size_t)row * N);
    float s = 0.f;
#pragma unroll
    for (int i = 0; i < 8; ++i) {
        float4 v = rp[t + i * 256];
        h4 h;
        h.x = (_Float16)v.x; h.y = (_Float16)v.y;
        h.z = (_Float16)v.z; h.w = (_Float16)v.w;
        hp[t + i * 256] = h;
        s += v.x + v.y + v.z + v.w;
    }
    for (int off = 32; off > 0; off >>= 1) s += __shfl_down(s, off, 64);
    __shared__ float red[4];
    if ((t & 63) == 0) red[t >> 6] = s;
    __syncthreads();
    if (t == 0) {
        float deg = red[0] + red[1] + red[2] + red[3] + 1.0f;
        deg = fmaxf(deg, 1.0f);
        dinv[row] = 1.0f / sqrtf(deg);
    }
}

// Zs[i][c] = dinv[i]*(x[i]@W1+b1)[c]; also Zt[c][i] = fp16(Zs[i][c]) (transposed)
__global__ __launch_bounds__(256) void k_z1(const float* __restrict__ x,
                                            const float* __restrict__ W1,
                                            const float* __restrict__ b1,
                                            const float* __restrict__ dinv,
                                            float* __restrict__ Zs,
                                            _Float16* __restrict__ Zt) {
    __shared__ float Ws[IN_DIM * HID];
    __shared__ float xs[8 * IN_DIM];
    __shared__ float zt_t[8 * HID];
    int t = threadIdx.x;
    int row0 = blockIdx.x * 8;
#pragma unroll
    for (int i = 0; i < 4; ++i)
        *(float4*)&Ws[(i * 256 + t) * 4] = *(const float4*)&W1[(i * 256 + t) * 4];
    *(float4*)&xs[t * 4] = *(const float4*)&x[(size_t)row0 * IN_DIM + t * 4];
    __syncthreads();
    int r = t >> 5, c = t & 31;
    float acc = b1[c];
#pragma unroll 8
    for (int k = 0; k < IN_DIM; ++k) acc = fmaf(xs[r * IN_DIM + k], Ws[k * HID + c], acc);
    int row = row0 + r;
    float v = dinv[row] * acc;
    Zs[(size_t)row * HID + c] = v;
    zt_t[r * HID + c] = v;
    __syncthreads();
    if (t < HID) {
        union { _Float16 h[8]; uint4 u; } pk;
#pragma unroll
        for (int rr = 0; rr < 8; ++rr) pk.h[rr] = (_Float16)zt_t[rr * HID + t];
        *(uint4*)(Zt + (size_t)t * N + row0) = pk.u;
    }
}

// Zs[i][c] = dinv[i]*(H[i]@W2+b2)[c]; Zt transposed fp16.
__global__ __launch_bounds__(256) void k_z2(const float* __restrict__ Hin,
                                            const float* __restrict__ W2,
                                            const float* __restrict__ b2,
                                            const float* __restrict__ dinv,
                                            float* __restrict__ Zs,
                                            _Float16* __restrict__ Zt) {
    __shared__ float Ws[HID * HID];
    __shared__ float hs[8 * HID];
    __shared__ float zt_t[8 * HID];
    int t = threadIdx.x;
    int row0 = blockIdx.x * 8;
    *(float4*)&Ws[t * 4] = *(const float4*)&W2[t * 4];
    if (t < 64) *(float4*)&hs[t * 4] = *(const float4*)&Hin[(size_t)row0 * HID + t * 4];
    __syncthreads();
    int r = t >> 5, c = t & 31;
    float acc = b2[c];
#pragma unroll
    for (int k = 0; k < HID; ++k) acc = fmaf(hs[r * HID + k], Ws[k * HID + c], acc);
    int row = row0 + r;
    float v = dinv[row] * acc;
    Zs[(size_t)row * HID + c] = v;
    zt_t[r * HID + c] = v;
    __syncthreads();
    if (t < HID) {
        union { _Float16 h[8]; uint4 u; } pk;
#pragma unroll
        for (int rr = 0; rr < 8; ++rr) pk.h[rr] = (_Float16)zt_t[rr * HID + t];
        *(uint4*)(Zt + (size_t)t * N + row0) = pk.u;
    }
}

// H[r][c] = relu(dinv[r] * (sum_k adjh[r][k]*Zt[c][k] + Zs[r][c]))
// Wave owns 4 rows, full K. Lane l covers k=8l..8l+7 per 512-k window.
// A: coalesced 1KB global loads direct to regs. B: Zt window [32][512] fp16
// in LDS, double-buffered. acc[4][32] MUST stay statically indexed (VGPRs) —
// round-2 dynamic index spilled it to scratch (1.1 GB HBM write traffic).
__global__ __launch_bounds__(256, 2) void k_spmm(const _Float16* __restrict__ adjh,
                                                 const _Float16* __restrict__ Ztg,
                                                 const float* __restrict__ Zs,
                                                 const float* __restrict__ dinv,
                                                 float* __restrict__ H) {
    __shared__ __align__(16) char smem[66560];  // max(2*32*512*2, 4*64*65*4)
    _Float16* zb = (_Float16*)smem;             // [2][32][WIN]
    float* scr = (float*)smem;                  // [4 waves][64][RSTRIDE]

    int t = threadIdx.x;
    int wv = t >> 6, ln = t & 63;
    int row0 = blockIdx.x * 16 + wv * 4;

    float acc[4][32];
#pragma unroll
    for (int r = 0; r < 4; ++r)
#pragma unroll
        for (int c = 0; c < 32; ++c) acc[r][c] = 0.f;

    // stage window 0 into buffer 0
#pragma unroll
    for (int i = 0; i < 8; ++i) {
        int id = i * 256 + t;
        int c = id >> 6;
        int kk = (id & 63) * 8;
        *(uint4*)(zb + c * WIN + kk) = *(const uint4*)(Ztg + (size_t)c * N + kk);
    }
    __syncthreads();

    for (int w = 0; w < NWIN; ++w) {
        if (w + 1 < NWIN) {
            _Float16* dst = zb + ((w + 1) & 1) * 32 * WIN;
#pragma unroll
            for (int i = 0; i < 8; ++i) {
                int id = i * 256 + t;
                int c = id >> 6;
                int kk = (id & 63) * 8;
                *(uint4*)(dst + c * WIN + kk) =
                    *(const uint4*)(Ztg + (size_t)c * N + (w + 1) * WIN + kk);
            }
        }
        const _Float16* B = zb + (w & 1) * 32 * WIN;

        uint4 a[4];
#pragma unroll
        for (int r = 0; r < 4; ++r)
            a[r] = *(const uint4*)(adjh + (size_t)(row0 + r) * N + w * WIN + ln * 8);
        h2 ah[4][4];
#pragma unroll
        for (int r = 0; r < 4; ++r) {
            ah[r][0] = bch2(a[r].x); ah[r][1] = bch2(a[r].y);
            ah[r][2] = bch2(a[r].z); ah[r][3] = bch2(a[r].w);
        }

#pragma unroll 4
        for (int c = 0; c < 32; ++c) {
            uint4 b = *(const uint4*)(B + c * WIN + ln * 8);
            h2 b0 = bch2(b.x), b1 = bch2(b.y), b2 = bch2(b.z), b3 = bch2(b.w);
#pragma unroll
            for (int r = 0; r < 4; ++r) {
                float s = acc[r][c];
                s = dot2acc(ah[r][0], b0, s);
                s = dot2acc(ah[r][1], b1, s);
                s = dot2acc(ah[r][2], b2, s);
                s = dot2acc(ah[r][3], b3, s);
                acc[r][c] = s;
            }
        }
        __syncthreads();
    }

    // cross-lane reduction: 2 phases of 2 rows each, via LDS transpose.
    // Fully unrolled: acc indices must remain compile-time constants.
    float* sw = scr + wv * (64 * RSTRIDE);
#pragma unroll
    for (int p = 0; p < 2; ++p) {
#pragma unroll
        for (int i = 0; i < 64; ++i) sw[i * RSTRIDE + ln] = acc[2 * p + (i >> 5)][i & 31];
        __syncthreads();
        float s = 0.f;
#pragma unroll
        for (int j = 0; j < 64; ++j) s += sw[ln * RSTRIDE + j];
        int row = row0 + 2 * p + (ln >> 5);
        int col = ln & 31;
        float val = dinv[row] * (s + Zs[(size_t)row * HID + col]);
        H[(size_t)row * HID + col] = fmaxf(val, 0.f);
        __syncthreads();
    }
}

// out[i] = H[i] @ W3 + b3
__global__ __launch_bounds__(256) void k_out(const float* __restrict__ H,
                                             const float* __restrict__ W3,
                                             const float* __restrict__ b3,
                                             float* __restrict__ out) {
    int i = blockIdx.x * 256 + threadIdx.x;
    const float4* hr = (const float4*)(H + (size_t)i * HID);
    const float4* w = (const float4*)W3;
    float acc = b3[0];
#pragma unroll
    for (int kk = 0; kk < 8; ++kk) {
        float4 h = hr[kk], ww = w[kk];
        acc += h.x * ww.x + h.y * ww.y + h.z * ww.z + h.w * ww.w;
    }
    out[i] = acc;
}

extern "C" void kernel_launch(void* const* d_in, const int* in_sizes, int n_in,
                              void* d_out, int out_size, void* d_ws, size_t ws_size,
                              hipStream_t stream) {
    const float* x   = (const float*)d_in[0];
    const float* adj = (const float*)d_in[1];
    const float* W1  = (const float*)d_in[2];
    const float* b1  = (const float*)d_in[3];
    const float* W2  = (const float*)d_in[4];
    const float* b2  = (const float*)d_in[5];
    const float* W3  = (const float*)d_in[6];
    const float* b3  = (const float*)d_in[7];
    float* out = (float*)d_out;

    char* ws = (char*)d_ws;
    float* dinv   = (float*)ws;                       ws += 8192 * sizeof(float);
    _Float16* adjh = (_Float16*)ws;                   ws += (size_t)N * N * sizeof(_Float16);
    float* Zs     = (float*)ws;                       ws += (size_t)N * HID * sizeof(float);
    _Float16* Zt  = (_Float16*)ws;                    ws += (size_t)N * HID * sizeof(_Float16);
    float* H      = (float*)ws;

    k_prep<<<N, 256, 0, stream>>>(adj, adjh, dinv);
    k_z1<<<N / 8, 256, 0, stream>>>(x, W1, b1, dinv, Zs, Zt);
    k_spmm<<<N / 16, 256, 0, stream>>>(adjh, Zt, Zs, dinv, H);
    k_z2<<<N / 8, 256, 0, stream>>>(H, W2, b2, dinv, Zs, Zt);
    k_spmm<<<N / 16, 256, 0, stream>>>(adjh, Zt, Zs, dinv, H);
    k_out<<<N / 256, 256, 0, stream>>>(H, W3, b3, out);
}

// Round 4
// 659.700 us; speedup vs baseline: 1.7203x; 1.7203x over previous
//
#include <hip/hip_runtime.h>
#include <math.h>

#define N 8192
#define IN_DIM 128
#define HID 32

#define WIN 512           // k-window per stage
#define NWIN (N / WIN)    // 16
#define RSTRIDE 65        // reduction scratch stride (odd: conflict-free)

typedef _Float16 h2 __attribute__((ext_vector_type(2)));
typedef _Float16 h4 __attribute__((ext_vector_type(4)));

__device__ __forceinline__ h2 bch2(unsigned u) {
    union { unsigned u; h2 h; } x; x.u = u; return x.h;
}

#if defined(__has_builtin)
#if __has_builtin(__builtin_amdgcn_fdot2)
#define HAVE_FDOT2 1
#endif
#endif

__device__ __forceinline__ float dot2acc(h2 a, h2 b, float c) {
#ifdef HAVE_FDOT2
    return __builtin_amdgcn_fdot2(a, b, c, false);
#else
    return fmaf((float)a.x, (float)b.x, fmaf((float)a.y, (float)b.y, c));
#endif
}

// dinv[i] = 1/sqrt(1 + sum_j adj[i][j]); also write fp16 copy of adj.
__global__ __launch_bounds__(256) void k_prep(const float* __restrict__ adj,
                                              _Float16* __restrict__ adjh,
                                              float* __restrict__ dinv) {
    int row = blockIdx.x;
    int t = threadIdx.x;
    const float4* rp = (const float4*)(adj + (size_t)row * N);
    h4* hp = (h4*)(adjh + (size_t)row * N);
    float s = 0.f;
#pragma unroll
    for (int i = 0; i < 8; ++i) {
        float4 v = rp[t + i * 256];
        h4 h;
        h.x = (_Float16)v.x; h.y = (_Float16)v.y;
        h.z = (_Float16)v.z; h.w = (_Float16)v.w;
        hp[t + i * 256] = h;
        s += v.x + v.y + v.z + v.w;
    }
    for (int off = 32; off > 0; off >>= 1) s += __shfl_down(s, off, 64);
    __shared__ float red[4];
    if ((t & 63) == 0) red[t >> 6] = s;
    __syncthreads();
    if (t == 0) {
        float deg = red[0] + red[1] + red[2] + red[3] + 1.0f;
        deg = fmaxf(deg, 1.0f);
        dinv[row] = 1.0f / sqrtf(deg);
    }
}

// Zs[i][c] = dinv[i]*(x[i]@W1+b1)[c]; also Zt[c][i] = fp16(Zs[i][c]) (transposed)
__global__ __launch_bounds__(256) void k_z1(const float* __restrict__ x,
                                            const float* __restrict__ W1,
                                            const float* __restrict__ b1,
                                            const float* __restrict__ dinv,
                                            float* __restrict__ Zs,
                                            _Float16* __restrict__ Zt) {
    __shared__ float Ws[IN_DIM * HID];
    __shared__ float xs[8 * IN_DIM];
    __shared__ float zt_t[8 * HID];
    int t = threadIdx.x;
    int row0 = blockIdx.x * 8;
#pragma unroll
    for (int i = 0; i < 4; ++i)
        *(float4*)&Ws[(i * 256 + t) * 4] = *(const float4*)&W1[(i * 256 + t) * 4];
    *(float4*)&xs[t * 4] = *(const float4*)&x[(size_t)row0 * IN_DIM + t * 4];
    __syncthreads();
    int r = t >> 5, c = t & 31;
    float acc = b1[c];
#pragma unroll 8
    for (int k = 0; k < IN_DIM; ++k) acc = fmaf(xs[r * IN_DIM + k], Ws[k * HID + c], acc);
    int row = row0 + r;
    float v = dinv[row] * acc;
    Zs[(size_t)row * HID + c] = v;
    zt_t[r * HID + c] = v;
    __syncthreads();
    if (t < HID) {
        union { _Float16 h[8]; uint4 u; } pk;
#pragma unroll
        for (int rr = 0; rr < 8; ++rr) pk.h[rr] = (_Float16)zt_t[rr * HID + t];
        *(uint4*)(Zt + (size_t)t * N + row0) = pk.u;
    }
}

// Zs[i][c] = dinv[i]*(H[i]@W2+b2)[c]; Zt transposed fp16.
__global__ __launch_bounds__(256) void k_z2(const float* __restrict__ Hin,
                                            const float* __restrict__ W2,
                                            const float* __restrict__ b2,
                                            const float* __restrict__ dinv,
                                            float* __restrict__ Zs,
                                            _Float16* __restrict__ Zt) {
    __shared__ float Ws[HID * HID];
    __shared__ float hs[8 * HID];
    __shared__ float zt_t[8 * HID];
    int t = threadIdx.x;
    int row0 = blockIdx.x * 8;
    *(float4*)&Ws[t * 4] = *(const float4*)&W2[t * 4];
    if (t < 64) *(float4*)&hs[t * 4] = *(const float4*)&Hin[(size_t)row0 * HID + t * 4];
    __syncthreads();
    int r = t >> 5, c = t & 31;
    float acc = b2[c];
#pragma unroll
    for (int k = 0; k < HID; ++k) acc = fmaf(hs[r * HID + k], Ws[k * HID + c], acc);
    int row = row0 + r;
    float v = dinv[row] * acc;
    Zs[(size_t)row * HID + c] = v;
    zt_t[r * HID + c] = v;
    __syncthreads();
    if (t < HID) {
        union { _Float16 h[8]; uint4 u; } pk;
#pragma unroll
        for (int rr = 0; rr < 8; ++rr) pk.h[rr] = (_Float16)zt_t[rr * HID + t];
        *(uint4*)(Zt + (size_t)t * N + row0) = pk.u;
    }
}

// H[r][c] = relu(dinv[r] * (sum_k adjh[r][k]*Zt[c][k] + Zs[r][c]))
// Wave owns 4 rows, full K. Lane l covers k=8l..8l+7 per 512-k window.
// A: coalesced 1KB global loads direct to regs. B: Zt window [32][512] fp16
// in LDS, double-buffered.
// CRITICAL: every index into acc[][] must be a compile-time constant — any
// runtime index (incl. partial-unroll induction vars, rounds 2&3 bug) spills
// the whole array to scratch (1.1 GB HBM RMW traffic, 88 VGPRs, 10x slower).
__global__ __launch_bounds__(256, 2) void k_spmm(const _Float16* __restrict__ adjh,
                                                 const _Float16* __restrict__ Ztg,
                                                 const float* __restrict__ Zs,
                                                 const float* __restrict__ dinv,
                                                 float* __restrict__ H) {
    __shared__ __align__(16) char smem[66560];  // max(2*32*512*2, 4*64*65*4)
    _Float16* zb = (_Float16*)smem;             // [2][32][WIN]
    float* scr = (float*)smem;                  // [4 waves][64][RSTRIDE]

    int t = threadIdx.x;
    int wv = t >> 6, ln = t & 63;
    int row0 = blockIdx.x * 16 + wv * 4;

    float acc[4][32];
#pragma unroll
    for (int r = 0; r < 4; ++r)
#pragma unroll
        for (int c = 0; c < 32; ++c) acc[r][c] = 0.f;

    // stage window 0 into buffer 0
#pragma unroll
    for (int i = 0; i < 8; ++i) {
        int id = i * 256 + t;
        int c = id >> 6;
        int kk = (id & 63) * 8;
        *(uint4*)(zb + c * WIN + kk) = *(const uint4*)(Ztg + (size_t)c * N + kk);
    }
    __syncthreads();

#pragma unroll 2
    for (int w = 0; w < NWIN; ++w) {
        if (w + 1 < NWIN) {
            _Float16* dst = zb + ((w + 1) & 1) * 32 * WIN;
#pragma unroll
            for (int i = 0; i < 8; ++i) {
                int id = i * 256 + t;
                int c = id >> 6;
                int kk = (id & 63) * 8;
                *(uint4*)(dst + c * WIN + kk) =
                    *(const uint4*)(Ztg + (size_t)c * N + (w + 1) * WIN + kk);
            }
        }
        const _Float16* B = zb + (w & 1) * 32 * WIN;

        uint4 a[4];
#pragma unroll
        for (int r = 0; r < 4; ++r)
            a[r] = *(const uint4*)(adjh + (size_t)(row0 + r) * N + w * WIN + ln * 8);
        h2 ah[4][4];
#pragma unroll
        for (int r = 0; r < 4; ++r) {
            ah[r][0] = bch2(a[r].x); ah[r][1] = bch2(a[r].y);
            ah[r][2] = bch2(a[r].z); ah[r][3] = bch2(a[r].w);
        }

        // FULL unroll (32): c must be compile-time so acc stays in VGPRs.
#pragma unroll
        for (int c = 0; c < 32; ++c) {
            uint4 b = *(const uint4*)(B + c * WIN + ln * 8);
            h2 b0 = bch2(b.x), b1 = bch2(b.y), b2 = bch2(b.z), b3 = bch2(b.w);
#pragma unroll
            for (int r = 0; r < 4; ++r) {
                float s = acc[r][c];
                s = dot2acc(ah[r][0], b0, s);
                s = dot2acc(ah[r][1], b1, s);
                s = dot2acc(ah[r][2], b2, s);
                s = dot2acc(ah[r][3], b3, s);
                acc[r][c] = s;
            }
        }
        __syncthreads();
    }

    // cross-lane reduction: 2 phases of 2 rows each, via LDS transpose.
    float* sw = scr + wv * (64 * RSTRIDE);
#pragma unroll
    for (int p = 0; p < 2; ++p) {
#pragma unroll
        for (int i = 0; i < 64; ++i) sw[i * RSTRIDE + ln] = acc[2 * p + (i >> 5)][i & 31];
        __syncthreads();
        float s = 0.f;
#pragma unroll
        for (int j = 0; j < 64; ++j) s += sw[ln * RSTRIDE + j];
        int row = row0 + 2 * p + (ln >> 5);
        int col = ln & 31;
        float val = dinv[row] * (s + Zs[(size_t)row * HID + col]);
        H[(size_t)row * HID + col] = fmaxf(val, 0.f);
        __syncthreads();
    }
}

// out[i] = H[i] @ W3 + b3
__global__ __launch_bounds__(256) void k_out(const float* __restrict__ H,
                                             const float* __restrict__ W3,
                                             const float* __restrict__ b3,
                                             float* __restrict__ out) {
    int i = blockIdx.x * 256 + threadIdx.x;
    const float4* hr = (const float4*)(H + (size_t)i * HID);
    const float4* w = (const float4*)W3;
    float acc = b3[0];
#pragma unroll
    for (int kk = 0; kk < 8; ++kk) {
        float4 h = hr[kk], ww = w[kk];
        acc += h.x * ww.x + h.y * ww.y + h.z * ww.z + h.w * ww.w;
    }
    out[i] = acc;
}

extern "C" void kernel_launch(void* const* d_in, const int* in_sizes, int n_in,
                              void* d_out, int out_size, void* d_ws, size_t ws_size,
                              hipStream_t stream) {
    const float* x   = (const float*)d_in[0];
    const float* adj = (const float*)d_in[1];
    const float* W1  = (const float*)d_in[2];
    const float* b1  = (const float*)d_in[3];
    const float* W2  = (const float*)d_in[4];
    const float* b2  = (const float*)d_in[5];
    const float* W3  = (const float*)d_in[6];
    const float* b3  = (const float*)d_in[7];
    float* out = (float*)d_out;

    char* ws = (char*)d_ws;
    float* dinv   = (float*)ws;                       ws += 8192 * sizeof(float);
    _Float16* adjh = (_Float16*)ws;                   ws += (size_t)N * N * sizeof(_Float16);
    float* Zs     = (float*)ws;                       ws += (size_t)N * HID * sizeof(float);
    _Float16* Zt  = (_Float16*)ws;                    ws += (size_t)N * HID * sizeof(_Float16);
    float* H      = (float*)ws;

    k_prep<<<N, 256, 0, stream>>>(adj, adjh, dinv);
    k_z1<<<N / 8, 256, 0, stream>>>(x, W1, b1, dinv, Zs, Zt);
    k_spmm<<<N / 16, 256, 0, stream>>>(adjh, Zt, Zs, dinv, H);
    k_z2<<<N / 8, 256, 0, stream>>>(H, W2, b2, dinv, Zs, Zt);
    k_spmm<<<N / 16, 256, 0, stream>>>(adjh, Zt, Zs, dinv, H);
    k_out<<<N / 256, 256, 0, stream>>>(H, W3, b3, out);
}